// Round 4
// baseline (480.924 us; speedup 1.0000x reference)
//
#include <hip/hip_runtime.h>

// Problem constants (fixed shapes from the reference file)
#define BB 32
#define SS 1024
#define HH 384
#define MAXLEN 8192
#define H4 (HH / 4)                 // 96 float4 per row
#define OUT0 (BB * MAXLEN * HH)     // 100663296 floats: the expanded output
#define MEL_OFF OUT0                // 32 floats: mel_len (as f32)
#define MASK_OFF (OUT0 + BB)        // 262144 floats: mel_mask
#define FRAMES_PER_BLK 1024         // each block expands 1024 frames of one batch
#define NBLK (BB * (MAXLEN / FRAMES_PER_BLK))   // 32 * 8 = 256 blocks

// Native 16B vector type: __builtin_nontemporal_store rejects HIP's float4
// (struct-wrapped), but accepts clang ext_vector_type.
typedef float vfloat4 __attribute__((ext_vector_type(4)));

// Fully fused: block (b, s) scans batch b's durations (redundant per slice,
// but the 4 KB dur row is cache-hot), searches its 1024 frames, then streams
// its 1.5 MB output slice. No workspace, no inter-kernel serialization.
// NOTE: bool inputs arrive widened to int32 (R1's absmax==1.0 proved the
// byte-wise read wrong) -> mel_mask as const int*.
__global__ __launch_bounds__(1024) void k_fused(
    const vfloat4* __restrict__ x4,
    const int* __restrict__ dur,
    const int* __restrict__ mel_mask_in,
    float* __restrict__ out)
{
    __shared__ int cum[SS];
    __shared__ int idxl[FRAMES_PER_BLK];

    const int blk = blockIdx.x;
    const int b = blk >> 3;             // batch
    const int s = blk & 7;              // slice: frames [s*1024, s*1024+1024)
    const int tid = threadIdx.x;

    cum[tid] = dur[b * SS + tid];
    // Hillis-Steele inclusive scan over 1024 elements
    for (int off = 1; off < SS; off <<= 1) {
        __syncthreads();
        int v = (tid >= off) ? cum[tid - off] : 0;
        __syncthreads();
        cum[tid] += v;
    }
    __syncthreads();

    const int mel_len = cum[SS - 1];
    if (s == 0 && tid == 0) out[MEL_OFF + b] = (float)mel_len;

    const int t = s * FRAMES_PER_BLK + tid;     // this thread's frame
    // mask passthrough (coalesced)
    out[MASK_OFF + b * MAXLEN + t] = mel_mask_in[b * MAXLEN + t] ? 1.0f : 0.0f;

    // searchsorted(cum, t, side='right'): first j with cum[j] > t
    int lo = 0, hi = SS;
    while (lo < hi) {
        int mid = (lo + hi) >> 1;
        if (cum[mid] <= t) lo = mid + 1; else hi = mid;
    }
    int idx = (lo < SS) ? lo : (SS - 1);
    idxl[tid] = (t < mel_len) ? idx : -1;
    __syncthreads();

    // Expand: 1024 frames x 96 float4 = 98304 items, 96 per thread.
    // j = tid + k*1024: per-wave fl is (near-)uniform -> idxl read broadcasts;
    // x gather and nontemporal store are fully coalesced.
    const size_t out_base = (size_t)(b * MAXLEN + s * FRAMES_PER_BLK) * H4;
    const size_t x_base = (size_t)b * SS * H4;
    vfloat4* __restrict__ out4 = (vfloat4*)out;
    for (int j = tid; j < FRAMES_PER_BLK * H4; j += 1024) {
        const int fl = j / H4;          // local frame
        const int c  = j - fl * H4;
        const int id = idxl[fl];
        vfloat4 v = (vfloat4)(0.f);
        if (id >= 0) v = x4[x_base + (size_t)id * H4 + c];
        __builtin_nontemporal_store(v, &out4[out_base + j]);
    }
}

extern "C" void kernel_launch(void* const* d_in, const int* in_sizes, int n_in,
                              void* d_out, int out_size, void* d_ws, size_t ws_size,
                              hipStream_t stream) {
    // setup_inputs order: x, src_mask, mel_mask, duration_target, pitch_target, max_len
    const float* x = (const float*)d_in[0];
    const int* mel_mask_in = (const int*)d_in[2];
    const int* dur = (const int*)d_in[3];
    float* out = (float*)d_out;

    k_fused<<<NBLK, 1024, 0, stream>>>((const vfloat4*)x, dur, mel_mask_in, out);
}

// Round 5
// 446.900 us; speedup vs baseline: 1.0761x; 1.0761x over previous
//
#include <hip/hip_runtime.h>

// Problem constants (fixed shapes from the reference file)
#define BB 32
#define SS 1024
#define HH 384
#define MAXLEN 8192
#define H4 (HH / 4)                 // 96 float4 per row
#define OUT0 (BB * MAXLEN * HH)     // 100663296 floats: the expanded output
#define MEL_OFF OUT0                // 32 floats: mel_len (as f32)
#define MASK_OFF (OUT0 + BB)        // 262144 floats: mel_mask

// Native 16B vector type: __builtin_nontemporal_store rejects HIP's float4
// (struct-wrapped), but accepts clang ext_vector_type.
typedef float vfloat4 __attribute__((ext_vector_type(4)));

// ---------------------------------------------------------------------------
// k_prep: one block per batch. Inclusive scan of durations in LDS, emit
// mel_len (f32), searchsorted idx per frame (-1 when t >= mel_len), mask.
// bool inputs arrive widened to int32 (R1 absmax==1.0 proved byte-read wrong).
// ---------------------------------------------------------------------------
__global__ __launch_bounds__(1024) void k_prep(
    const int* __restrict__ dur,
    const int* __restrict__ mel_mask_in,
    float* __restrict__ out,
    int* __restrict__ idxbuf)
{
    __shared__ int cum[SS];
    const int b = blockIdx.x;
    const int tid = threadIdx.x;

    cum[tid] = dur[b * SS + tid];
    for (int off = 1; off < SS; off <<= 1) {
        __syncthreads();
        int v = (tid >= off) ? cum[tid - off] : 0;
        __syncthreads();
        cum[tid] += v;
    }
    __syncthreads();

    const int mel_len = cum[SS - 1];
    if (tid == 0) out[MEL_OFF + b] = (float)mel_len;

    for (int k = 0; k < MAXLEN / SS; ++k) {
        const int t = tid + k * SS;
        int lo = 0, hi = SS;
        while (lo < hi) {
            int mid = (lo + hi) >> 1;
            if (cum[mid] <= t) lo = mid + 1; else hi = mid;
        }
        int idx = (lo < SS) ? lo : (SS - 1);
        idxbuf[b * MAXLEN + t] = (t < mel_len) ? idx : -1;
        out[MASK_OFF + b * MAXLEN + t] = mel_mask_in[b * MAXLEN + t] ? 1.0f : 0.0f;
    }
}

// ---------------------------------------------------------------------------
// k_expand: 16 frames per block EXACTLY (256 thr x 6 float4 = 1536 = 16*96).
// - frame idx staged once in LDS (1 read/frame instead of 96)
// - no frame straddles a block; a block's ~5 source rows stay L1-hot
// - XCD swizzle: physical L -> W so each XCD owns a contiguous 1/8 of out
// - nontemporal stores: out is write-once, keep L2 for x gathers
// ---------------------------------------------------------------------------
#define FPB 16
#define ITEMS 6
#define NB_EXP (BB * MAXLEN / FPB)   // 16384 blocks
__global__ __launch_bounds__(256) void k_expand(
    const vfloat4* __restrict__ x4,
    const int* __restrict__ idxbuf,
    vfloat4* __restrict__ out4)
{
    __shared__ int sidx[FPB];
    const int L = blockIdx.x;
    const int W = (L & 7) * (NB_EXP / 8) + (L >> 3);
    const int f0 = W * FPB;                 // global frame base (= b*8192 + t0)
    if (threadIdx.x < FPB) sidx[threadIdx.x] = idxbuf[f0 + threadIdx.x];
    __syncthreads();

    const int b = f0 >> 13;                 // 8192 % 16 == 0: no batch straddle
    const size_t xb = (size_t)b * SS * H4;
    const size_t ob = (size_t)f0 * H4;
#pragma unroll
    for (int k = 0; k < ITEMS; ++k) {
        const int j = (int)threadIdx.x + k * 256;   // 0..1535, coalesced per iter
        const int fl = j / H4;                      // local frame 0..15
        const int c  = j - fl * H4;
        const int id = sidx[fl];
        vfloat4 v = (vfloat4)(0.f);
        if (id >= 0) v = x4[xb + (size_t)id * H4 + c];
        __builtin_nontemporal_store(v, &out4[ob + j]);
    }
}

extern "C" void kernel_launch(void* const* d_in, const int* in_sizes, int n_in,
                              void* d_out, int out_size, void* d_ws, size_t ws_size,
                              hipStream_t stream) {
    // setup_inputs order: x, src_mask, mel_mask, duration_target, pitch_target, max_len
    const float* x = (const float*)d_in[0];
    const int* mel_mask_in = (const int*)d_in[2];
    const int* dur = (const int*)d_in[3];
    float* out = (float*)d_out;
    int* idxbuf = (int*)d_ws;   // BB*MAXLEN ints = 1 MB

    k_prep<<<BB, 1024, 0, stream>>>(dur, mel_mask_in, out, idxbuf);
    k_expand<<<NB_EXP, 256, 0, stream>>>((const vfloat4*)x, idxbuf, (vfloat4*)out);
}

// Round 6
// 439.157 us; speedup vs baseline: 1.0951x; 1.0176x over previous
//
#include <hip/hip_runtime.h>

// Problem constants (fixed shapes from the reference file)
#define BB 32
#define SS 1024
#define HH 384
#define MAXLEN 8192
#define H4 (HH / 4)                 // 96 float4 per row
#define OUT0 (BB * MAXLEN * HH)     // 100663296 floats: the expanded output
#define MEL_OFF OUT0                // 32 floats: mel_len (as f32)
#define MASK_OFF (OUT0 + BB)        // 262144 floats: mel_mask

// Native 16B vector type: __builtin_nontemporal_store rejects HIP's float4
// (struct-wrapped), but accepts clang ext_vector_type.
typedef float vfloat4 __attribute__((ext_vector_type(4)));

// ---------------------------------------------------------------------------
// k_prep: 256 blocks = (batch b, slice s of 1024 frames). Each block
// redundantly scans batch b's 1024 durations — wave shuffle scan (6 steps)
// + 16-partial LDS combine: 2 barriers instead of R5's 20. Then each thread
// searchsorted's exactly one frame t = s*1024+tid and writes idx + mask.
// bool inputs arrive widened to int32 (R1 absmax==1.0 proved byte-read wrong).
// ---------------------------------------------------------------------------
__global__ __launch_bounds__(1024) void k_prep(
    const int* __restrict__ dur,
    const int* __restrict__ mel_mask_in,
    float* __restrict__ out,
    int* __restrict__ idxbuf)
{
    __shared__ int cum[SS];
    __shared__ int wsum[16];

    const int blk = blockIdx.x;
    const int b = blk >> 3;
    const int s = blk & 7;
    const int tid = threadIdx.x;
    const int lane = tid & 63;
    const int wid = tid >> 6;           // 16 waves

    // wave-level inclusive scan of this thread's duration
    int v = dur[b * SS + tid];
#pragma unroll
    for (int o = 1; o < 64; o <<= 1) {
        int u = __shfl_up(v, o, 64);
        if (lane >= o) v += u;
    }
    if (lane == 63) wsum[wid] = v;
    __syncthreads();

    // wave 0 scans the 16 wave sums
    if (wid == 0 && lane < 16) {
        int w = wsum[lane];
#pragma unroll
        for (int o = 1; o < 16; o <<= 1) {
            int u = __shfl_up(w, o, 64);
            if (lane >= o) w += u;
        }
        wsum[lane] = w;
    }
    __syncthreads();

    const int off = (wid > 0) ? wsum[wid - 1] : 0;
    cum[tid] = v + off;
    __syncthreads();

    const int mel_len = wsum[15];
    if (s == 0 && tid == 0) out[MEL_OFF + b] = (float)mel_len;

    // one frame per thread
    const int t = s * 1024 + tid;
    int lo = 0, hi = SS;
    while (lo < hi) {
        int mid = (lo + hi) >> 1;
        if (cum[mid] <= t) lo = mid + 1; else hi = mid;
    }
    int idx = (lo < SS) ? lo : (SS - 1);
    idxbuf[b * MAXLEN + t] = (t < mel_len) ? idx : -1;
    out[MASK_OFF + b * MAXLEN + t] = mel_mask_in[b * MAXLEN + t] ? 1.0f : 0.0f;
}

// ---------------------------------------------------------------------------
// k_expand (unchanged from R5 — R3==R5 showed it's HBM-bound):
// 16 frames per block exactly (256 thr x 6 float4 = 1536 = 16*96).
// idx staged in LDS; XCD swizzle for L2 locality; nontemporal stores.
// ---------------------------------------------------------------------------
#define FPB 16
#define ITEMS 6
#define NB_EXP (BB * MAXLEN / FPB)   // 16384 blocks
__global__ __launch_bounds__(256) void k_expand(
    const vfloat4* __restrict__ x4,
    const int* __restrict__ idxbuf,
    vfloat4* __restrict__ out4)
{
    __shared__ int sidx[FPB];
    const int L = blockIdx.x;
    const int W = (L & 7) * (NB_EXP / 8) + (L >> 3);
    const int f0 = W * FPB;                 // global frame base (= b*8192 + t0)
    if (threadIdx.x < FPB) sidx[threadIdx.x] = idxbuf[f0 + threadIdx.x];
    __syncthreads();

    const int b = f0 >> 13;                 // 8192 % 16 == 0: no batch straddle
    const size_t xb = (size_t)b * SS * H4;
    const size_t ob = (size_t)f0 * H4;
#pragma unroll
    for (int k = 0; k < ITEMS; ++k) {
        const int j = (int)threadIdx.x + k * 256;   // 0..1535, coalesced per iter
        const int fl = j / H4;                      // local frame 0..15
        const int c  = j - fl * H4;
        const int id = sidx[fl];
        vfloat4 v = (vfloat4)(0.f);
        if (id >= 0) v = x4[xb + (size_t)id * H4 + c];
        __builtin_nontemporal_store(v, &out4[ob + j]);
    }
}

extern "C" void kernel_launch(void* const* d_in, const int* in_sizes, int n_in,
                              void* d_out, int out_size, void* d_ws, size_t ws_size,
                              hipStream_t stream) {
    // setup_inputs order: x, src_mask, mel_mask, duration_target, pitch_target, max_len
    const float* x = (const float*)d_in[0];
    const int* mel_mask_in = (const int*)d_in[2];
    const int* dur = (const int*)d_in[3];
    float* out = (float*)d_out;
    int* idxbuf = (int*)d_ws;   // BB*MAXLEN ints = 1 MB

    k_prep<<<BB * 8, 1024, 0, stream>>>(dur, mel_mask_in, out, idxbuf);
    k_expand<<<NB_EXP, 256, 0, stream>>>((const vfloat4*)x, idxbuf, (vfloat4*)out);
}